// Round 2
// baseline (4955.798 us; speedup 1.0000x reference)
//
#include <hip/hip_runtime.h>
#include <cmath>

#define Bn   128
#define Cn   8
#define Fn   58
#define Tn   249
#define RCn  24
#define FT   14442      // Fn*Tn
#define CFT  115536     // Cn*Fn*Tn
#define OUTB 346608     // 3*CFT per-batch output
#define IH   60
#define IW   251

// ---------------------------------------------------------------------------
// differ = concat([x[...,:1], W_diff@x + b_diff (shift) - x[...,:-1]], -1)
// Q = wq@differ + bq ; K = wk@differ + bk ; V = differ
// ---------------------------------------------------------------------------
__global__ void k_differ_qk(const float* __restrict__ x,
                            const float* __restrict__ w_diff, const float* __restrict__ b_diff,
                            const float* __restrict__ wq, const float* __restrict__ bq,
                            const float* __restrict__ wk, const float* __restrict__ bk,
                            float* __restrict__ V, float* __restrict__ Q, float* __restrict__ K) {
    int gid = blockIdx.x * blockDim.x + threadIdx.x;
    if (gid >= Bn * FT) return;
    int b  = gid / FT;
    int ft = gid % FT;
    int t  = ft % Tn;
    const float* xb = x + (size_t)b * CFT + ft;

    float xv[Cn], d[Cn];
    #pragma unroll
    for (int c = 0; c < Cn; c++) xv[c] = xb[c * FT];

    if (t == 0) {
        #pragma unroll
        for (int c = 0; c < Cn; c++) d[c] = xv[c];
    } else {
        #pragma unroll
        for (int o = 0; o < Cn; o++) {
            float s = b_diff[o];
            #pragma unroll
            for (int c = 0; c < Cn; c++) s += w_diff[o * Cn + c] * xv[c];
            d[o] = s - xb[o * FT - 1];
        }
    }

    float* Vb = V + (size_t)b * CFT + ft;
    float* Qb = Q + (size_t)b * CFT + ft;
    float* Kb = K + (size_t)b * CFT + ft;
    #pragma unroll
    for (int o = 0; o < Cn; o++) {
        Vb[o * FT] = d[o];
        float q = bq[o], k = bk[o];
        #pragma unroll
        for (int c = 0; c < Cn; c++) { q += wq[o * Cn + c] * d[c]; k += wk[o * Cn + c] * d[c]; }
        Qb[o * FT] = q;
        Kb[o * FT] = k;
    }
}

// ---------------------------------------------------------------------------
// Column-owner register GEMM v2 (R1 post-mortem):
//   out[b, j0+j, l..l+VL) (+)= sum_m A[b, j0+j, m] * V[b, m, l..l+VL)
// Changes vs R1: (1) m-chunked LDS staging (64-row chunks) -> LDS 9KB not
// 66-72KB, occupancy 2 -> 5+ blocks/CU; (2) VL columns/thread via float2/4
// loads so each broadcast LDS weight read feeds VL FMAs (R1 was LDS-read
// throughput-bound at 2 floats LDS per FMA); (3) whole inner loop guarded by
// wave-uniform `act` so idle waves skip the ds_reads entirely (R1's idle
// wave still issued all LDS reads = 25% of the LDS bill).
// ---------------------------------------------------------------------------
template<int AN, int RG, int VL>
__global__ void __launch_bounds__(256)
k_gemm(const float* __restrict__ A, long long aStride,   // 0 => batch-shared weights
       const float* __restrict__ bias,                   // nullptr => no bias
       const float* __restrict__ V, long long vStride, int dv,
       float* __restrict__ out, long long oStride, int add,
       int gx, int gy)
{
    constexpr int RGP = (RG + 4) & ~3;   // padded LDS row, 16B-aligned
    __shared__ float As[64][RGP];

    int nblk = gridDim.x;
    int bid  = blockIdx.x;
    if ((nblk & 7) == 0) {               // bijective XCD swizzle
        int cpx = nblk >> 3;
        bid = (bid & 7) * cpx + (bid >> 3);
    }
    int gxy = gx * gy;
    int b   = bid / gxy;
    int rem = bid - b * gxy;
    int j0  = (rem / gx) * RG;
    int l   = (rem % gx) * (256 * VL) + threadIdx.x * VL;
    bool act = (l + VL <= dv);           // all dv are multiples of VL

    const float* Ab = A + (size_t)b * aStride;
    const float* Vb = V + (size_t)b * vStride + l;

    float acc[RG][VL];
    #pragma unroll
    for (int j = 0; j < RG; j++)
        #pragma unroll
        for (int e = 0; e < VL; e++) acc[j][e] = 0.f;

    for (int m0 = 0; m0 < AN; m0 += 64) {
        int mc = min(64, AN - m0);
        for (int idx = threadIdx.x; idx < RG * 64; idx += 256) {
            int j = idx >> 6, mi = idx & 63;     // lanes along mi -> coalesced A reads
            float w = 0.f;
            if (j0 + j < AN && mi < mc) w = Ab[(size_t)(j0 + j) * AN + m0 + mi];
            As[mi][j] = w;
        }
        __syncthreads();
        if (act) {
            const float* Vp = Vb + (size_t)m0 * dv;
            if constexpr (AN <= 64) {
                #pragma unroll
                for (int mm = 0; mm < AN; mm++) {
                    float x[VL];
                    if constexpr (VL == 4) {
                        float4 xv = *(const float4*)(Vp + (size_t)mm * dv);
                        x[0] = xv.x; x[1] = xv.y; x[2] = xv.z; x[3] = xv.w;
                    } else {
                        float2 xv = *(const float2*)(Vp + (size_t)mm * dv);
                        x[0] = xv.x; x[1] = xv.y;
                    }
                    #pragma unroll
                    for (int j = 0; j < RG; j++) {
                        float w = As[mm][j];
                        #pragma unroll
                        for (int e = 0; e < VL; e++) acc[j][e] += w * x[e];
                    }
                }
            } else {
                #pragma unroll 4
                for (int mm = 0; mm < mc; mm++) {
                    float x[VL];
                    if constexpr (VL == 4) {
                        float4 xv = *(const float4*)(Vp + (size_t)mm * dv);
                        x[0] = xv.x; x[1] = xv.y; x[2] = xv.z; x[3] = xv.w;
                    } else {
                        float2 xv = *(const float2*)(Vp + (size_t)mm * dv);
                        x[0] = xv.x; x[1] = xv.y;
                    }
                    #pragma unroll
                    for (int j = 0; j < RG; j++) {
                        float w = As[mm][j];
                        #pragma unroll
                        for (int e = 0; e < VL; e++) acc[j][e] += w * x[e];
                    }
                }
            }
        }
        __syncthreads();
    }

    if (!act) return;
    float* ob = out + (size_t)b * oStride + l;
    #pragma unroll
    for (int j = 0; j < RG; j++) {
        if (j0 + j < AN) {
            float bv = bias ? bias[j0 + j] : 0.f;
            float* op = ob + (size_t)(j0 + j) * dv;
            if (add) {
                #pragma unroll
                for (int e = 0; e < VL; e++) op[e] += acc[j][e] + bv;
            } else {
                if constexpr (VL == 4) {
                    *(float4*)op = make_float4(acc[j][0] + bv, acc[j][1] + bv,
                                               acc[j][2] + bv, acc[j][3] + bv);
                } else {
                    *(float2*)op = make_float2(acc[j][0] + bv, acc[j][1] + bv);
                }
            }
        }
    }
}

// ---------------------------------------------------------------------------
// Stride-2 conv engine, same v2 structure. Interleaved w0/w1 LDS rows so one
// b128 broadcast = {w0[j],w1[j],w0[j+1],w1[j+1]} feeds 8 FMAs (VL=4 cols via
// two float4 X loads). Only threads with 4t < d_out run the inner loop.
// ---------------------------------------------------------------------------
template<int AN, int RG>
__global__ void __launch_bounds__(256)
k_gemm_s2(const float* __restrict__ W, const float* __restrict__ bias,
          const float* __restrict__ X, long long xStride, int d_in, int d_out,
          float* __restrict__ out, long long oStride, int gy)
{
    constexpr int RW = 2 * RG + 4;       // interleaved row, 16B-aligned
    __shared__ float Ws[64][RW];

    int nblk = gridDim.x;
    int bid  = blockIdx.x;
    if ((nblk & 7) == 0) {
        int cpx = nblk >> 3;
        bid = (bid & 7) * cpx + (bid >> 3);
    }
    int b  = bid / gy;
    int j0 = (bid % gy) * RG;
    int t  = threadIdx.x;
    bool act = (4 * t < d_out);          // d_out % 4 == 0

    const float* Xb = X + (size_t)b * xStride + 8 * t;

    float acc[RG][4];
    #pragma unroll
    for (int j = 0; j < RG; j++)
        #pragma unroll
        for (int e = 0; e < 4; e++) acc[j][e] = 0.f;

    for (int m0 = 0; m0 < AN; m0 += 64) {
        int mc = min(64, AN - m0);
        for (int idx = t; idx < 2 * RG * 64; idx += 256) {
            int mi = idx & 63, rest = idx >> 6;
            int j = rest >> 1, tap = rest & 1;
            float w = 0.f;
            if (j0 + j < AN && mi < mc)
                w = W[((size_t)(j0 + j) * AN + m0 + mi) * 2 + tap];
            Ws[mi][2 * j + tap] = w;
        }
        __syncthreads();
        if (act) {
            const float* Xp = Xb + (size_t)m0 * d_in;
            #pragma unroll 2
            for (int mm = 0; mm < mc; mm++) {
                float4 x0 = *(const float4*)(Xp + (size_t)mm * d_in);
                float4 x1 = *(const float4*)(Xp + (size_t)mm * d_in + 4);
                #pragma unroll
                for (int j = 0; j < RG; j++) {
                    float w0 = Ws[mm][2 * j], w1 = Ws[mm][2 * j + 1];
                    acc[j][0] += w0 * x0.x + w1 * x0.y;
                    acc[j][1] += w0 * x0.z + w1 * x0.w;
                    acc[j][2] += w0 * x1.x + w1 * x1.y;
                    acc[j][3] += w0 * x1.z + w1 * x1.w;
                }
            }
        }
        __syncthreads();
    }

    if (!act) return;
    float* ob = out + (size_t)b * oStride + 4 * t;
    #pragma unroll
    for (int j = 0; j < RG; j++) {
        if (j0 + j < AN) {
            float bv = bias[j0 + j];
            *(float4*)(ob + (size_t)(j0 + j) * d_out) =
                make_float4(acc[j][0] + bv, acc[j][1] + bv,
                            acc[j][2] + bv, acc[j][3] + bv);
        }
    }
}

// ---------------------------------------------------------------------------
// Scores split-K: SP[bz,r,c] = sum_k Q[b,r,k]K[b,c,k]. 64x64 tile, 4x4/thread,
// float4 LDS fragment reads (rows 68 floats = 16B-aligned).
// ---------------------------------------------------------------------------
__global__ void __launch_bounds__(256)
k_scores_sk(const float* __restrict__ Q, const float* __restrict__ K,
            float* __restrict__ SP, int n, int d, int kz_n, int chunk, int sQ) {
    __shared__ float Qs[16][68];
    __shared__ float Ks[16][68];
    int bz = blockIdx.z;
    int b  = bz / kz_n, kz = bz % kz_n;
    int k0 = kz * chunk, k1 = min(d, k0 + chunk);
    int r0 = blockIdx.x * 64, c0 = blockIdx.y * 64;
    int tx = threadIdx.x & 15, ty = threadIdx.x >> 4;
    int lrow = threadIdx.x >> 2;
    int lk   = (threadIdx.x & 3) * 4;
    const float* Qr = Q + (size_t)b * sQ + (size_t)min(r0 + lrow, n - 1) * d;
    const float* Kr = K + (size_t)b * sQ + (size_t)min(c0 + lrow, n - 1) * d;
    bool qok = (r0 + lrow) < n;
    bool kok = (c0 + lrow) < n;
    float acc[4][4] = {};

    for (int kk = k0; kk < k1; kk += 16) {
        #pragma unroll
        for (int u = 0; u < 4; u++) {
            int gk = kk + lk + u;
            bool gv = gk < k1;
            Qs[lk + u][lrow] = (qok && gv) ? Qr[gk] : 0.f;
            Ks[lk + u][lrow] = (kok && gv) ? Kr[gk] : 0.f;
        }
        __syncthreads();
        #pragma unroll
        for (int k = 0; k < 16; k++) {
            float4 q4 = *(const float4*)&Qs[k][ty * 4];
            float4 k4 = *(const float4*)&Ks[k][tx * 4];
            float aq[4] = {q4.x, q4.y, q4.z, q4.w};
            float ak[4] = {k4.x, k4.y, k4.z, k4.w};
            #pragma unroll
            for (int i = 0; i < 4; i++)
                #pragma unroll
                for (int j = 0; j < 4; j++) acc[i][j] += aq[i] * ak[j];
        }
        __syncthreads();
    }
    float* Sb = SP + (size_t)bz * n * n;
    #pragma unroll
    for (int i = 0; i < 4; i++) {
        int r = r0 + ty * 4 + i;
        #pragma unroll
        for (int j = 0; j < 4; j++) {
            int c = c0 + tx * 4 + j;
            if (r < n && c < n) Sb[(size_t)r * n + c] = acc[i][j];
        }
    }
}

// ---------------------------------------------------------------------------
// Combine split-K partials (no scale — softmax folds 1/sqrt(d)).
// ---------------------------------------------------------------------------
__global__ void k_scombine(const float* __restrict__ SP, float* __restrict__ S,
                           int n, int kz_n) {
    int idx = blockIdx.x * 256 + threadIdx.x;
    int nn = n * n;
    if (idx >= Bn * nn) return;
    int b = idx / nn, rc = idx % nn;
    float s = 0.f;
    for (int kz = 0; kz < kz_n; kz++) s += SP[((size_t)b * kz_n + kz) * nn + rc];
    S[(size_t)b * nn + rc] = s;
}

// ---------------------------------------------------------------------------
// c-branch gram: 8x8 over d=FT, 8 l-chunks of partials.
// ---------------------------------------------------------------------------
#define C_LZ 8
__global__ void k_gram8(const float* __restrict__ Q, const float* __restrict__ K,
                        float* __restrict__ SP) {
    int b  = blockIdx.x / C_LZ;
    int lz = blockIdx.x % C_LZ;
    int g  = threadIdx.x >> 6;
    int p  = threadIdx.x & 63;
    int r  = p >> 3, c = p & 7;
    const float* Qb = Q + (size_t)b * CFT + (size_t)r * FT;
    const float* Kb = K + (size_t)b * CFT + (size_t)c * FT;
    int chunk = (FT + C_LZ - 1) / C_LZ;
    int l0 = lz * chunk, l1 = min(FT, l0 + chunk);
    float acc = 0.f;
    for (int l = l0 + g; l < l1; l += 4) acc += Qb[l] * Kb[l];
    __shared__ float red[256];
    red[threadIdx.x] = acc;
    __syncthreads();
    if (threadIdx.x < 64) {
        float s = red[p] + red[64 + p] + red[128 + p] + red[192 + p];
        SP[(size_t)blockIdx.x * 64 + p] = s;
    }
}

// ---------------------------------------------------------------------------
// column softmax in-place (axis=1), folds 1/sqrt(d). v2: 256-thread blocks =
// 64 cols x 4 row-groups (R1 used 64-thread blocks, 3 serial strided passes).
// ---------------------------------------------------------------------------
__global__ void __launch_bounds__(256)
k_softmax(float* __restrict__ S, int n, int cb, float scale) {
    __shared__ float red[4][64];
    int b  = blockIdx.x / cb;
    int tc = threadIdx.x & 63;
    int g  = threadIdx.x >> 6;
    int c  = (blockIdx.x % cb) * 64 + tc;
    bool act = c < n;
    float* Sb = S + (size_t)b * n * n;

    float mx = -1e30f;
    if (act) for (int r = g; r < n; r += 4) mx = fmaxf(mx, Sb[(size_t)r * n + c]);
    red[g][tc] = mx;
    __syncthreads();
    mx = fmaxf(fmaxf(red[0][tc], red[1][tc]), fmaxf(red[2][tc], red[3][tc]));
    __syncthreads();

    float sum = 0.f;
    if (act) for (int r = g; r < n; r += 4) {
        float e = __expf((Sb[(size_t)r * n + c] - mx) * scale);
        Sb[(size_t)r * n + c] = e;
        sum += e;
    }
    red[g][tc] = sum;
    __syncthreads();
    float inv = 1.f / (red[0][tc] + red[1][tc] + red[2][tc] + red[3][tc]);
    if (act) for (int r = g; r < n; r += 4) Sb[(size_t)r * n + c] *= inv;
}

// ---------------------------------------------------------------------------
// xr spatial mean per (b, rc)
// ---------------------------------------------------------------------------
__global__ void k_mean(const float* __restrict__ inp, const float* __restrict__ w_res,
                       const float* __restrict__ b_res, const float* __restrict__ bn_gamma,
                       const float* __restrict__ bn_beta, const float* __restrict__ bn_mean,
                       const float* __restrict__ bn_var, float* __restrict__ meanbuf) {
    int b  = blockIdx.x / RCn;
    int rc = blockIdx.x % RCn;
    float w[9];
    #pragma unroll
    for (int i = 0; i < 9; i++) w[i] = w_res[rc * 9 + i];
    float g    = bn_gamma[rc] * rsqrtf(bn_var[rc] + 1e-5f);
    float bias = (b_res[rc] - bn_mean[rc]) * g + bn_beta[rc];
    const float* ib = inp + (size_t)b * IH * IW;

    float sum = 0.f;
    for (int idx = threadIdx.x; idx < FT; idx += 256) {
        int f = idx / Tn, t = idx % Tn;
        const float* p = ib + f * IW + t;
        float v = w[0]*p[0]     + w[1]*p[1]     + w[2]*p[2]
                + w[3]*p[IW]    + w[4]*p[IW+1]  + w[5]*p[IW+2]
                + w[6]*p[2*IW]  + w[7]*p[2*IW+1]+ w[8]*p[2*IW+2];
        sum += v * g + bias;
    }
    __shared__ float red[256];
    red[threadIdx.x] = sum;
    __syncthreads();
    for (int s = 128; s > 0; s >>= 1) {
        if (threadIdx.x < s) red[threadIdx.x] += red[threadIdx.x + s];
        __syncthreads();
    }
    if (threadIdx.x == 0) meanbuf[b * RCn + rc] = red[0] / (float)FT;
}

// ---------------------------------------------------------------------------
// dyReLU coefficient MLP
// ---------------------------------------------------------------------------
__global__ void k_coef(const float* __restrict__ meanbuf, const float* __restrict__ w1,
                       const float* __restrict__ b1, const float* __restrict__ w2,
                       const float* __restrict__ b2, float* __restrict__ coef) {
    int b = blockIdx.x;
    int k = threadIdx.x;
    if (k >= 4 * RCn) return;
    const float* th = meanbuf + b * RCn;
    float h[6];
    #pragma unroll
    for (int j = 0; j < 6; j++) {
        float s = b1[j];
        #pragma unroll
        for (int c = 0; c < RCn; c++) s += th[c] * w1[j * RCn + c];
        h[j] = fmaxf(s, 0.f);
    }
    float s = b2[k];
    #pragma unroll
    for (int j = 0; j < 6; j++) s += h[j] * w2[k * 6 + j];
    float g2 = 2.f / (1.f + __expf(-s)) - 1.f;
    const float lam[4] = {1.f, 1.f, 0.5f, 0.5f};
    const float ini[4] = {1.f, 0.f, 0.f, 0.f};
    coef[b * 96 + k] = g2 * lam[k & 3] + ini[k & 3];
}

// ---------------------------------------------------------------------------
// recompute conv+BN, apply dyReLU, out += xr
// ---------------------------------------------------------------------------
__global__ void k_xr_add(const float* __restrict__ inp, const float* __restrict__ w_res,
                         const float* __restrict__ b_res, const float* __restrict__ bn_gamma,
                         const float* __restrict__ bn_beta, const float* __restrict__ bn_mean,
                         const float* __restrict__ bn_var, const float* __restrict__ coef,
                         float* __restrict__ out) {
    int gid = blockIdx.x * blockDim.x + threadIdx.x;
    if (gid >= Bn * RCn * FT) return;
    int t   = gid % Tn;
    int tmp = gid / Tn;
    int f   = tmp % Fn;  tmp /= Fn;
    int rc  = tmp % RCn;
    int b   = tmp / RCn;

    const float* wp = w_res + rc * 9;
    float g    = bn_gamma[rc] * rsqrtf(bn_var[rc] + 1e-5f);
    float bias = (b_res[rc] - bn_mean[rc]) * g + bn_beta[rc];
    const float* p = inp + (size_t)b * IH * IW + f * IW + t;
    float v = wp[0]*p[0]    + wp[1]*p[1]      + wp[2]*p[2]
            + wp[3]*p[IW]   + wp[4]*p[IW+1]   + wp[5]*p[IW+2]
            + wp[6]*p[2*IW] + wp[7]*p[2*IW+1] + wp[8]*p[2*IW+2];
    float xv = v * g + bias;

    const float* cf = coef + ((size_t)b * RCn + rc) * 4;
    float r = fmaxf(xv * cf[0] + cf[2], xv * cf[1] + cf[3]);
    out[gid] += r;
}

// ---------------------------------------------------------------------------
extern "C" void kernel_launch(void* const* d_in, const int* in_sizes, int n_in,
                              void* d_out, int out_size, void* d_ws, size_t ws_size,
                              hipStream_t stream) {
    const float* x        = (const float*)d_in[0];
    const float* inp      = (const float*)d_in[1];
    const float* w_diff   = (const float*)d_in[2];
    const float* b_diff   = (const float*)d_in[3];
    const float* w_res    = (const float*)d_in[4];
    const float* b_res    = (const float*)d_in[5];
    const float* bn_gamma = (const float*)d_in[6];
    const float* bn_beta  = (const float*)d_in[7];
    const float* bn_mean  = (const float*)d_in[8];
    const float* bn_var   = (const float*)d_in[9];
    const float* dy_w1    = (const float*)d_in[10];
    const float* dy_b1    = (const float*)d_in[11];
    const float* dy_w2    = (const float*)d_in[12];
    const float* dy_b2    = (const float*)d_in[13];
    const float* wq       = (const float*)d_in[14];
    const float* bq       = (const float*)d_in[15];
    const float* wk       = (const float*)d_in[16];
    const float* bk       = (const float*)d_in[17];
    const float* fq0_w    = (const float*)d_in[18];
    const float* fq0_b    = (const float*)d_in[19];
    const float* fk0_w    = (const float*)d_in[20];
    const float* fk0_b    = (const float*)d_in[21];
    const float* cq0_w    = (const float*)d_in[22];
    const float* cq0_b    = (const float*)d_in[23];
    const float* ck0_w    = (const float*)d_in[24];
    const float* ck0_b    = (const float*)d_in[25];
    const float* tq0_w    = (const float*)d_in[26];
    const float* tq0_b    = (const float*)d_in[27];
    const float* tk0_w    = (const float*)d_in[28];
    const float* tk0_b    = (const float*)d_in[29];
    const float* tq1_w    = (const float*)d_in[30];
    const float* tq1_b    = (const float*)d_in[31];
    const float* tk1_w    = (const float*)d_in[32];
    const float* tk1_b    = (const float*)d_in[33];

    float* out = (float*)d_out;
    float* ws  = (float*)d_ws;

    const size_t NB = (size_t)Bn * CFT;
    float* V       = ws;
    float* Q       = ws + NB;
    float* K       = ws + 2 * NB;
    float* Qp      = ws + 3 * NB;
    float* Kp      = ws + 4 * NB;
    float* S       = ws + 5 * NB;                       // up to Bn*Tn*Tn floats
    float* SP      = S + 4200000;                        // split-K partials (f/c only)
    float* meanbuf = S + (size_t)Bn * Tn * Tn;
    float* coef    = meanbuf + Bn * RCn;

    {
        int total = Bn * FT;
        k_differ_qk<<<dim3((total + 255) / 256), dim3(256), 0, stream>>>(
            x, w_diff, b_diff, wq, bq, wk, bk, V, Q, K);
    }

    // scores + softmax + apply for the f / t branches
    auto attend_nt = [&](const float* Qv, const float* Kv, int n, int dq, int sQ,
                         int KZ, int sec, int add) {
        float scale = 1.0f / sqrtf((float)dq);
        int chunk = ((dq + KZ * 32 - 1) / (KZ * 32)) * 32;
        float* SPb = (KZ == 1) ? S : SP;
        dim3 g1((n + 63) / 64, (n + 63) / 64, Bn * KZ);
        k_scores_sk<<<g1, dim3(256), 0, stream>>>(Qv, Kv, SPb, n, dq, KZ, chunk, sQ);
        if (KZ > 1) {
            int nn = n * n;
            k_scombine<<<dim3((Bn * nn + 255) / 256), dim3(256), 0, stream>>>(SPb, S, n, KZ);
        }
        int cb = (n + 63) / 64;
        k_softmax<<<dim3(Bn * cb), dim3(256), 0, stream>>>(S, n, cb, scale);
        if (n == Fn) {
            // dv=1992: gx=2 (1024 cols/block), gy=2 (29 rows each)
            k_gemm<Fn, 29, 4><<<dim3(Bn * 4), dim3(256), 0, stream>>>(
                S, (long long)Fn * Fn, nullptr, V, CFT, 1992,
                out + (size_t)sec * CFT, OUTB, add, 2, 2);
        } else {
            // n=249, dv=464: gx=1 (116 active threads x4), gy=11 (24 rows each)
            k_gemm<Tn, 24, 4><<<dim3(Bn * 11), dim3(256), 0, stream>>>(
                S, (long long)Tn * Tn, nullptr, V, CFT, 464,
                out + (size_t)sec * CFT, OUTB, add, 1, 11);
        }
    };

    auto attend_c = [&](const float* Qv, const float* Kv, int add) {
        k_gram8<<<dim3(Bn * C_LZ), dim3(256), 0, stream>>>(Qv, Kv, SP);
        k_scombine<<<dim3((Bn * 64 + 255) / 256), dim3(256), 0, stream>>>(SP, S, Cn, C_LZ);
        k_softmax<<<dim3(Bn), dim3(256), 0, stream>>>(S, Cn, 1, 1.0f / sqrtf((float)FT));
        // dv=14442 (float2 align only): VL=2, gx=29
        k_gemm<Cn, Cn, 2><<<dim3(Bn * 29), dim3(256), 0, stream>>>(
            S, (long long)Cn * Cn, nullptr, V, CFT, FT, out + CFT, OUTB, add, 29, 1);
    };

    // ---- f branch: n=58, d=1992, sec=0, split-K 8
    attend_nt(Q, K, Fn, 1992, CFT, 8, 0, 0);
    k_gemm<Fn, 29, 4><<<dim3(Bn * 4), dim3(256), 0, stream>>>(
        fq0_w, 0, fq0_b, Q, CFT, 1992, Qp, CFT, 0, 2, 2);
    k_gemm<Fn, 29, 4><<<dim3(Bn * 4), dim3(256), 0, stream>>>(
        fk0_w, 0, fk0_b, K, CFT, 1992, Kp, CFT, 0, 2, 2);
    attend_nt(Qp, Kp, Fn, 1992, CFT, 8, 0, 1);

    // ---- c branch: n=8, d=14442, sec=1
    attend_c(Q, K, 0);
    k_gemm<Cn, Cn, 2><<<dim3(Bn * 29), dim3(256), 0, stream>>>(
        cq0_w, 0, cq0_b, Q, CFT, FT, Qp, CFT, 0, 29, 1);
    k_gemm<Cn, Cn, 2><<<dim3(Bn * 29), dim3(256), 0, stream>>>(
        ck0_w, 0, ck0_b, K, CFT, FT, Kp, CFT, 0, 29, 1);
    attend_c(Qp, Kp, 1);

    // ---- t branch: n=249, dv=464, sec=2
    attend_nt(Q, K, Tn, 464, CFT, 1, 2, 0);
    k_gemm<Tn, 24, 4><<<dim3(Bn * 11), dim3(256), 0, stream>>>(
        tq0_w, 0, tq0_b, Q, CFT, 464, Qp, CFT, 0, 1, 11);
    k_gemm<Tn, 24, 4><<<dim3(Bn * 11), dim3(256), 0, stream>>>(
        tk0_w, 0, tk0_b, K, CFT, 464, Kp, CFT, 0, 1, 11);
    attend_nt(Qp, Kp, Tn, 464, CFT, 1, 2, 1);
    // stride-2 conv: d_out=232, RG=16 -> gy=16
    k_gemm_s2<Tn, 16><<<dim3(Bn * 16), dim3(256), 0, stream>>>(
        tq1_w, tq1_b, Q, CFT, 464, 232, Qp, (long long)Tn * 232, 16);
    k_gemm_s2<Tn, 16><<<dim3(Bn * 16), dim3(256), 0, stream>>>(
        tk1_w, tk1_b, K, CFT, 464, 232, Kp, (long long)Tn * 232, 16);
    attend_nt(Qp, Kp, Tn, 232, Tn * 232, 1, 2, 1);

    // ---- xr residual path
    k_mean<<<dim3(Bn * RCn), dim3(256), 0, stream>>>(
        inp, w_res, b_res, bn_gamma, bn_beta, bn_mean, bn_var, meanbuf);
    k_coef<<<dim3(Bn), dim3(128), 0, stream>>>(meanbuf, dy_w1, dy_b1, dy_w2, dy_b2, coef);
    {
        int total = Bn * RCn * FT;
        k_xr_add<<<dim3((total + 255) / 256), dim3(256), 0, stream>>>(
            inp, w_res, b_res, bn_gamma, bn_beta, bn_mean, bn_var, coef, out);
    }
}

// Round 3
// 3333.162 us; speedup vs baseline: 1.4868x; 1.4868x over previous
//
#include <hip/hip_runtime.h>
#include <cmath>

#define Bn   128
#define Cn   8
#define Fn   58
#define Tn   249
#define RCn  24
#define FT   14442      // Fn*Tn
#define CFT  115536     // Cn*Fn*Tn
#define OUTB 346608     // 3*CFT per-batch output
#define IH   60
#define IW   251

// ---------------------------------------------------------------------------
// differ = concat([x[...,:1], W_diff@x + b_diff (shift) - x[...,:-1]], -1)
// Q = wq@differ + bq ; K = wk@differ + bk ; V = differ
// ---------------------------------------------------------------------------
__global__ void k_differ_qk(const float* __restrict__ x,
                            const float* __restrict__ w_diff, const float* __restrict__ b_diff,
                            const float* __restrict__ wq, const float* __restrict__ bq,
                            const float* __restrict__ wk, const float* __restrict__ bk,
                            float* __restrict__ V, float* __restrict__ Q, float* __restrict__ K) {
    int gid = blockIdx.x * blockDim.x + threadIdx.x;
    if (gid >= Bn * FT) return;
    int b  = gid / FT;
    int ft = gid % FT;
    int t  = ft % Tn;
    const float* xb = x + (size_t)b * CFT + ft;

    float xv[Cn], d[Cn];
    #pragma unroll
    for (int c = 0; c < Cn; c++) xv[c] = xb[c * FT];

    if (t == 0) {
        #pragma unroll
        for (int c = 0; c < Cn; c++) d[c] = xv[c];
    } else {
        #pragma unroll
        for (int o = 0; o < Cn; o++) {
            float s = b_diff[o];
            #pragma unroll
            for (int c = 0; c < Cn; c++) s += w_diff[o * Cn + c] * xv[c];
            d[o] = s - xb[o * FT - 1];
        }
    }

    float* Vb = V + (size_t)b * CFT + ft;
    float* Qb = Q + (size_t)b * CFT + ft;
    float* Kb = K + (size_t)b * CFT + ft;
    #pragma unroll
    for (int o = 0; o < Cn; o++) {
        Vb[o * FT] = d[o];
        float q = bq[o], k = bk[o];
        #pragma unroll
        for (int c = 0; c < Cn; c++) { q += wq[o * Cn + c] * d[c]; k += wk[o * Cn + c] * d[c]; }
        Qb[o * FT] = q;
        Kb[o * FT] = k;
    }
}

// ---------------------------------------------------------------------------
// Column-owner register GEMM v3 (R2 post-mortem):
//   out[b, j0+j, l..l+VL) (+)= sum_m A[b, j0+j, m] * V[b, m, l..l+VL)
// Budget rules learned R1/R2:
//   - FMA:LDS-float ratio = VL; need VL=4 (1 shared LDS pipe vs 4 SIMDs/CU).
//   - acc = RG*VL must be <= 64 VGPRs; R2's 96/116-acc configs got capped at
//     92 VGPRs by the allocator (no waves bound) -> spill -> VALUBusy 15%.
//   - __launch_bounds__(256,4) pins the allocator at <=128 VGPRs.
// ---------------------------------------------------------------------------
template<int AN, int RG, int VL>
__global__ void __launch_bounds__(256, 4)
k_gemm(const float* __restrict__ A, long long aStride,   // 0 => batch-shared weights
       const float* __restrict__ bias,                   // nullptr => no bias
       const float* __restrict__ V, long long vStride, int dv,
       float* __restrict__ out, long long oStride, int add,
       int gx, int gy)
{
    constexpr int RGP = (RG + 4) & ~3;   // padded LDS row, 16B-aligned
    __shared__ float As[64][RGP];

    int nblk = gridDim.x;
    int bid  = blockIdx.x;
    if ((nblk & 7) == 0) {               // bijective XCD swizzle
        int cpx = nblk >> 3;
        bid = (bid & 7) * cpx + (bid >> 3);
    }
    int gxy = gx * gy;
    int b   = bid / gxy;
    int rem = bid - b * gxy;
    int j0  = (rem / gx) * RG;
    int l   = (rem % gx) * (256 * VL) + threadIdx.x * VL;
    bool act = (l + VL <= dv);           // dv % VL == 0 for all uses

    const float* Ab = A + (size_t)b * aStride;
    const float* Vb = V + (size_t)b * vStride + l;

    float acc[RG][VL];
    #pragma unroll
    for (int j = 0; j < RG; j++)
        #pragma unroll
        for (int e = 0; e < VL; e++) acc[j][e] = 0.f;

    for (int m0 = 0; m0 < AN; m0 += 64) {
        int mc = min(64, AN - m0);
        for (int idx = threadIdx.x; idx < RG * 64; idx += 256) {
            int j = idx >> 6, mi = idx & 63;     // lanes along mi -> coalesced A reads
            float w = 0.f;
            if (j0 + j < AN && mi < mc) w = Ab[(size_t)(j0 + j) * AN + m0 + mi];
            As[mi][j] = w;
        }
        __syncthreads();
        if (act) {
            const float* Vp = Vb + (size_t)m0 * dv;
            #pragma unroll 4
            for (int mm = 0; mm < mc; mm++) {
                float x[VL];
                if constexpr (VL == 4) {
                    float4 xv = *(const float4*)(Vp + (size_t)mm * dv);
                    x[0] = xv.x; x[1] = xv.y; x[2] = xv.z; x[3] = xv.w;
                } else {
                    float2 xv = *(const float2*)(Vp + (size_t)mm * dv);
                    x[0] = xv.x; x[1] = xv.y;
                }
                #pragma unroll
                for (int j = 0; j < RG; j++) {
                    float w = As[mm][j];
                    #pragma unroll
                    for (int e = 0; e < VL; e++) acc[j][e] += w * x[e];
                }
            }
        }
        __syncthreads();
    }

    if (!act) return;
    float* ob = out + (size_t)b * oStride + l;
    #pragma unroll
    for (int j = 0; j < RG; j++) {
        if (j0 + j < AN) {
            float bv = bias ? bias[j0 + j] : 0.f;
            float* op = ob + (size_t)(j0 + j) * dv;
            if (add) {
                #pragma unroll
                for (int e = 0; e < VL; e++) op[e] += acc[j][e] + bv;
            } else {
                if constexpr (VL == 4) {
                    *(float4*)op = make_float4(acc[j][0] + bv, acc[j][1] + bv,
                                               acc[j][2] + bv, acc[j][3] + bv);
                } else {
                    *(float2*)op = make_float2(acc[j][0] + bv, acc[j][1] + bv);
                }
            }
        }
    }
}

// ---------------------------------------------------------------------------
// Stride-2 conv v3: each WAVE owns RGW rows, its 58/64 lanes own 4 output
// cols each (R2 had 58/256 threads active). Per mm per thread: 4c x 2tap x
// RGW FMAs per 2*RGW broadcast LDS floats -> 4:1 ratio.
// ---------------------------------------------------------------------------
template<int AN, int RGW>
__global__ void __launch_bounds__(256, 4)
k_gemm_s2(const float* __restrict__ W, const float* __restrict__ bias,
          const float* __restrict__ X, long long xStride, int d_in, int d_out,
          float* __restrict__ out, long long oStride, int gy)
{
    constexpr int BR = 4 * RGW;              // rows per block
    __shared__ float Ws[64][2 * BR + 4];

    int nblk = gridDim.x;
    int bid  = blockIdx.x;
    if ((nblk & 7) == 0) {
        int cpx = nblk >> 3;
        bid = (bid & 7) * cpx + (bid >> 3);
    }
    int b    = bid / gy;
    int jb   = (bid % gy) * BR;
    int w    = threadIdx.x >> 6;
    int lane = threadIdx.x & 63;
    int j0   = jb + w * RGW;
    int l4   = lane * 4;
    bool act = l4 < d_out;                   // d_out=232 -> lanes 0..57

    const float* Xb = X + (size_t)b * xStride + 2 * l4;

    float acc[RGW][4];
    #pragma unroll
    for (int j = 0; j < RGW; j++)
        #pragma unroll
        for (int e = 0; e < 4; e++) acc[j][e] = 0.f;

    for (int m0 = 0; m0 < AN; m0 += 64) {
        int mc = min(64, AN - m0);
        for (int idx = threadIdx.x; idx < 2 * BR * 64; idx += 256) {
            int mi = idx & 63, rest = idx >> 6;
            int rj = rest >> 1, tap = rest & 1;
            float wv = 0.f;
            if (jb + rj < AN && mi < mc)
                wv = W[((size_t)(jb + rj) * AN + m0 + mi) * 2 + tap];
            Ws[mi][2 * rj + tap] = wv;
        }
        __syncthreads();
        if (act) {
            const float* Xp = Xb + (size_t)m0 * d_in;
            #pragma unroll 2
            for (int mm = 0; mm < mc; mm++) {
                float4 x0 = *(const float4*)(Xp + (size_t)mm * d_in);
                float4 x1 = *(const float4*)(Xp + (size_t)mm * d_in + 4);
                const float* wrow = &Ws[mm][2 * (w * RGW)];
                #pragma unroll
                for (int j = 0; j < RGW; j++) {
                    float w0 = wrow[2 * j], w1 = wrow[2 * j + 1];
                    acc[j][0] += w0 * x0.x + w1 * x0.y;
                    acc[j][1] += w0 * x0.z + w1 * x0.w;
                    acc[j][2] += w0 * x1.x + w1 * x1.y;
                    acc[j][3] += w0 * x1.z + w1 * x1.w;
                }
            }
        }
        __syncthreads();
    }

    if (!act) return;
    float* ob = out + (size_t)b * oStride + l4;
    #pragma unroll
    for (int j = 0; j < RGW; j++) {
        if (j0 + j < AN) {
            float bv = bias[j0 + j];
            *(float4*)(ob + (size_t)(j0 + j) * d_out) =
                make_float4(acc[j][0] + bv, acc[j][1] + bv,
                            acc[j][2] + bv, acc[j][3] + bv);
        }
    }
}

// ---------------------------------------------------------------------------
// t-branch scores: 128x128 tile, 8x8 per thread (64 FMA per 4x b128 = 4:1,
// replaces 64x64/4x4's 2:1 which was LDS-pipe-bound).
// ---------------------------------------------------------------------------
__global__ void __launch_bounds__(256, 4)
k_scores128(const float* __restrict__ Q, const float* __restrict__ K,
            float* __restrict__ S, int n, int d, int sQ) {
    __shared__ float Qs[16][132];
    __shared__ float Ks[16][132];
    int b  = blockIdx.z;
    int r0 = blockIdx.x * 128, c0 = blockIdx.y * 128;
    int tid = threadIdx.x;
    int tx = tid & 15, ty = tid >> 4;
    int lrow = tid >> 1;
    int lk   = (tid & 1) * 8;
    const float* Qr = Q + (size_t)b * sQ + (size_t)min(r0 + lrow, n - 1) * d;
    const float* Kr = K + (size_t)b * sQ + (size_t)min(c0 + lrow, n - 1) * d;

    float acc[8][8] = {};
    for (int kk = 0; kk < d; kk += 16) {
        #pragma unroll
        for (int h = 0; h < 2; h++) {
            int g = kk + lk + h * 4;
            float4 qv = make_float4(0.f, 0.f, 0.f, 0.f);
            float4 kv = make_float4(0.f, 0.f, 0.f, 0.f);
            if (g + 4 <= d) {                 // d % 4 == 0 for all uses
                qv = *(const float4*)(Qr + g);
                kv = *(const float4*)(Kr + g);
            }
            int kb = lk + h * 4;
            Qs[kb + 0][lrow] = qv.x; Qs[kb + 1][lrow] = qv.y;
            Qs[kb + 2][lrow] = qv.z; Qs[kb + 3][lrow] = qv.w;
            Ks[kb + 0][lrow] = kv.x; Ks[kb + 1][lrow] = kv.y;
            Ks[kb + 2][lrow] = kv.z; Ks[kb + 3][lrow] = kv.w;
        }
        __syncthreads();
        #pragma unroll
        for (int k = 0; k < 16; k++) {
            float4 qa = *(const float4*)&Qs[k][ty * 8];
            float4 qb = *(const float4*)&Qs[k][ty * 8 + 4];
            float4 ka = *(const float4*)&Ks[k][tx * 8];
            float4 kb4 = *(const float4*)&Ks[k][tx * 8 + 4];
            float aq[8] = {qa.x, qa.y, qa.z, qa.w, qb.x, qb.y, qb.z, qb.w};
            float ak[8] = {ka.x, ka.y, ka.z, ka.w, kb4.x, kb4.y, kb4.z, kb4.w};
            #pragma unroll
            for (int i = 0; i < 8; i++)
                #pragma unroll
                for (int j = 0; j < 8; j++) acc[i][j] += aq[i] * ak[j];
        }
        __syncthreads();
    }
    float* Sb = S + (size_t)b * n * n;
    #pragma unroll
    for (int i = 0; i < 8; i++) {
        int r = r0 + ty * 8 + i;
        if (r < n) {
            #pragma unroll
            for (int j = 0; j < 8; j++) {
                int c = c0 + tx * 8 + j;
                if (c < n) Sb[(size_t)r * n + c] = acc[i][j];
            }
        }
    }
}

// ---------------------------------------------------------------------------
// f-branch scores split-K (n=58 fits a 64-tile; kept from R1).
// ---------------------------------------------------------------------------
__global__ void __launch_bounds__(256)
k_scores_sk(const float* __restrict__ Q, const float* __restrict__ K,
            float* __restrict__ SP, int n, int d, int kz_n, int chunk, int sQ) {
    __shared__ float Qs[16][68];
    __shared__ float Ks[16][68];
    int bz = blockIdx.z;
    int b  = bz / kz_n, kz = bz % kz_n;
    int k0 = kz * chunk, k1 = min(d, k0 + chunk);
    int r0 = blockIdx.x * 64, c0 = blockIdx.y * 64;
    int tx = threadIdx.x & 15, ty = threadIdx.x >> 4;
    int lrow = threadIdx.x >> 2;
    int lk   = (threadIdx.x & 3) * 4;
    const float* Qr = Q + (size_t)b * sQ + (size_t)min(r0 + lrow, n - 1) * d;
    const float* Kr = K + (size_t)b * sQ + (size_t)min(c0 + lrow, n - 1) * d;
    bool qok = (r0 + lrow) < n;
    bool kok = (c0 + lrow) < n;
    float acc[4][4] = {};

    for (int kk = k0; kk < k1; kk += 16) {
        #pragma unroll
        for (int u = 0; u < 4; u++) {
            int gk = kk + lk + u;
            bool gv = gk < k1;
            Qs[lk + u][lrow] = (qok && gv) ? Qr[gk] : 0.f;
            Ks[lk + u][lrow] = (kok && gv) ? Kr[gk] : 0.f;
        }
        __syncthreads();
        #pragma unroll
        for (int k = 0; k < 16; k++) {
            float4 q4 = *(const float4*)&Qs[k][ty * 4];
            float4 k4 = *(const float4*)&Ks[k][tx * 4];
            float aq[4] = {q4.x, q4.y, q4.z, q4.w};
            float ak[4] = {k4.x, k4.y, k4.z, k4.w};
            #pragma unroll
            for (int i = 0; i < 4; i++)
                #pragma unroll
                for (int j = 0; j < 4; j++) acc[i][j] += aq[i] * ak[j];
        }
        __syncthreads();
    }
    float* Sb = SP + (size_t)bz * n * n;
    #pragma unroll
    for (int i = 0; i < 4; i++) {
        int r = r0 + ty * 4 + i;
        #pragma unroll
        for (int j = 0; j < 4; j++) {
            int c = c0 + tx * 4 + j;
            if (r < n && c < n) Sb[(size_t)r * n + c] = acc[i][j];
        }
    }
}

// ---------------------------------------------------------------------------
// Combine split-K partials (no scale — softmax folds 1/sqrt(d)).
// ---------------------------------------------------------------------------
__global__ void k_scombine(const float* __restrict__ SP, float* __restrict__ S,
                           int n, int kz_n) {
    int idx = blockIdx.x * 256 + threadIdx.x;
    int nn = n * n;
    if (idx >= Bn * nn) return;
    int b = idx / nn, rc = idx % nn;
    float s = 0.f;
    for (int kz = 0; kz < kz_n; kz++) s += SP[((size_t)b * kz_n + kz) * nn + rc];
    S[(size_t)b * nn + rc] = s;
}

// ---------------------------------------------------------------------------
// c-branch gram: 8x8 over d=FT, 8 l-chunks of partials.
// ---------------------------------------------------------------------------
#define C_LZ 8
__global__ void k_gram8(const float* __restrict__ Q, const float* __restrict__ K,
                        float* __restrict__ SP) {
    int b  = blockIdx.x / C_LZ;
    int lz = blockIdx.x % C_LZ;
    int g  = threadIdx.x >> 6;
    int p  = threadIdx.x & 63;
    int r  = p >> 3, c = p & 7;
    const float* Qb = Q + (size_t)b * CFT + (size_t)r * FT;
    const float* Kb = K + (size_t)b * CFT + (size_t)c * FT;
    int chunk = (FT + C_LZ - 1) / C_LZ;
    int l0 = lz * chunk, l1 = min(FT, l0 + chunk);
    float acc = 0.f;
    for (int l = l0 + g; l < l1; l += 4) acc += Qb[l] * Kb[l];
    __shared__ float red[256];
    red[threadIdx.x] = acc;
    __syncthreads();
    if (threadIdx.x < 64) {
        float s = red[p] + red[64 + p] + red[128 + p] + red[192 + p];
        SP[(size_t)blockIdx.x * 64 + p] = s;
    }
}

// ---------------------------------------------------------------------------
// column softmax (axis=1), folds 1/sqrt(d). Optional P-accumulation into
// Sacc (first ? P : Sacc+P) so each branch needs ONE apply (distributivity:
// sum_i softmax_i @ V = (sum_i softmax_i) @ V). Sacc==nullptr -> in-place.
// ---------------------------------------------------------------------------
__global__ void __launch_bounds__(256)
k_softmax(float* __restrict__ S, float* __restrict__ Sacc,
          int n, int cb, float scale, int first) {
    __shared__ float red[4][64];
    int b  = blockIdx.x / cb;
    int tc = threadIdx.x & 63;
    int g  = threadIdx.x >> 6;
    int c  = (blockIdx.x % cb) * 64 + tc;
    bool act = c < n;
    float* Sb = S + (size_t)b * n * n;

    float mx = -1e30f;
    if (act) for (int r = g; r < n; r += 4) mx = fmaxf(mx, Sb[(size_t)r * n + c]);
    red[g][tc] = mx;
    __syncthreads();
    mx = fmaxf(fmaxf(red[0][tc], red[1][tc]), fmaxf(red[2][tc], red[3][tc]));
    __syncthreads();

    float sum = 0.f;
    if (act) for (int r = g; r < n; r += 4) {
        float e = __expf((Sb[(size_t)r * n + c] - mx) * scale);
        Sb[(size_t)r * n + c] = e;
        sum += e;
    }
    red[g][tc] = sum;
    __syncthreads();
    float inv = 1.f / (red[0][tc] + red[1][tc] + red[2][tc] + red[3][tc]);
    if (act) {
        if (Sacc) {
            float* Ab = Sacc + (size_t)b * n * n;
            for (int r = g; r < n; r += 4) {
                float v = Sb[(size_t)r * n + c] * inv;
                size_t o = (size_t)r * n + c;
                Ab[o] = first ? v : (Ab[o] + v);
            }
        } else {
            for (int r = g; r < n; r += 4) Sb[(size_t)r * n + c] *= inv;
        }
    }
}

// ---------------------------------------------------------------------------
// xr spatial mean per (b, rc)
// ---------------------------------------------------------------------------
__global__ void k_mean(const float* __restrict__ inp, const float* __restrict__ w_res,
                       const float* __restrict__ b_res, const float* __restrict__ bn_gamma,
                       const float* __restrict__ bn_beta, const float* __restrict__ bn_mean,
                       const float* __restrict__ bn_var, float* __restrict__ meanbuf) {
    int b  = blockIdx.x / RCn;
    int rc = blockIdx.x % RCn;
    float w[9];
    #pragma unroll
    for (int i = 0; i < 9; i++) w[i] = w_res[rc * 9 + i];
    float g    = bn_gamma[rc] * rsqrtf(bn_var[rc] + 1e-5f);
    float bias = (b_res[rc] - bn_mean[rc]) * g + bn_beta[rc];
    const float* ib = inp + (size_t)b * IH * IW;

    float sum = 0.f;
    for (int idx = threadIdx.x; idx < FT; idx += 256) {
        int f = idx / Tn, t = idx % Tn;
        const float* p = ib + f * IW + t;
        float v = w[0]*p[0]     + w[1]*p[1]     + w[2]*p[2]
                + w[3]*p[IW]    + w[4]*p[IW+1]  + w[5]*p[IW+2]
                + w[6]*p[2*IW]  + w[7]*p[2*IW+1]+ w[8]*p[2*IW+2];
        sum += v * g + bias;
    }
    __shared__ float red[256];
    red[threadIdx.x] = sum;
    __syncthreads();
    for (int s = 128; s > 0; s >>= 1) {
        if (threadIdx.x < s) red[threadIdx.x] += red[threadIdx.x + s];
        __syncthreads();
    }
    if (threadIdx.x == 0) meanbuf[b * RCn + rc] = red[0] / (float)FT;
}

// ---------------------------------------------------------------------------
// dyReLU coefficient MLP
// ---------------------------------------------------------------------------
__global__ void k_coef(const float* __restrict__ meanbuf, const float* __restrict__ w1,
                       const float* __restrict__ b1, const float* __restrict__ w2,
                       const float* __restrict__ b2, float* __restrict__ coef) {
    int b = blockIdx.x;
    int k = threadIdx.x;
    if (k >= 4 * RCn) return;
    const float* th = meanbuf + b * RCn;
    float h[6];
    #pragma unroll
    for (int j = 0; j < 6; j++) {
        float s = b1[j];
        #pragma unroll
        for (int c = 0; c < RCn; c++) s += th[c] * w1[j * RCn + c];
        h[j] = fmaxf(s, 0.f);
    }
    float s = b2[k];
    #pragma unroll
    for (int j = 0; j < 6; j++) s += h[j] * w2[k * 6 + j];
    float g2 = 2.f / (1.f + __expf(-s)) - 1.f;
    const float lam[4] = {1.f, 1.f, 0.5f, 0.5f};
    const float ini[4] = {1.f, 0.f, 0.f, 0.f};
    coef[b * 96 + k] = g2 * lam[k & 3] + ini[k & 3];
}

// ---------------------------------------------------------------------------
// recompute conv+BN, apply dyReLU, out += xr
// ---------------------------------------------------------------------------
__global__ void k_xr_add(const float* __restrict__ inp, const float* __restrict__ w_res,
                         const float* __restrict__ b_res, const float* __restrict__ bn_gamma,
                         const float* __restrict__ bn_beta, const float* __restrict__ bn_mean,
                         const float* __restrict__ bn_var, const float* __restrict__ coef,
                         float* __restrict__ out) {
    int gid = blockIdx.x * blockDim.x + threadIdx.x;
    if (gid >= Bn * RCn * FT) return;
    int t   = gid % Tn;
    int tmp = gid / Tn;
    int f   = tmp % Fn;  tmp /= Fn;
    int rc  = tmp % RCn;
    int b   = tmp / RCn;

    const float* wp = w_res + rc * 9;
    float g    = bn_gamma[rc] * rsqrtf(bn_var[rc] + 1e-5f);
    float bias = (b_res[rc] - bn_mean[rc]) * g + bn_beta[rc];
    const float* p = inp + (size_t)b * IH * IW + f * IW + t;
    float v = wp[0]*p[0]    + wp[1]*p[1]      + wp[2]*p[2]
            + wp[3]*p[IW]   + wp[4]*p[IW+1]   + wp[5]*p[IW+2]
            + wp[6]*p[2*IW] + wp[7]*p[2*IW+1] + wp[8]*p[2*IW+2];
    float xv = v * g + bias;

    const float* cf = coef + ((size_t)b * RCn + rc) * 4;
    float r = fmaxf(xv * cf[0] + cf[2], xv * cf[1] + cf[3]);
    out[gid] += r;
}

// ---------------------------------------------------------------------------
extern "C" void kernel_launch(void* const* d_in, const int* in_sizes, int n_in,
                              void* d_out, int out_size, void* d_ws, size_t ws_size,
                              hipStream_t stream) {
    const float* x        = (const float*)d_in[0];
    const float* inp      = (const float*)d_in[1];
    const float* w_diff   = (const float*)d_in[2];
    const float* b_diff   = (const float*)d_in[3];
    const float* w_res    = (const float*)d_in[4];
    const float* b_res    = (const float*)d_in[5];
    const float* bn_gamma = (const float*)d_in[6];
    const float* bn_beta  = (const float*)d_in[7];
    const float* bn_mean  = (const float*)d_in[8];
    const float* bn_var   = (const float*)d_in[9];
    const float* dy_w1    = (const float*)d_in[10];
    const float* dy_b1    = (const float*)d_in[11];
    const float* dy_w2    = (const float*)d_in[12];
    const float* dy_b2    = (const float*)d_in[13];
    const float* wq       = (const float*)d_in[14];
    const float* bq       = (const float*)d_in[15];
    const float* wk       = (const float*)d_in[16];
    const float* bk       = (const float*)d_in[17];
    const float* fq0_w    = (const float*)d_in[18];
    const float* fq0_b    = (const float*)d_in[19];
    const float* fk0_w    = (const float*)d_in[20];
    const float* fk0_b    = (const float*)d_in[21];
    const float* cq0_w    = (const float*)d_in[22];
    const float* cq0_b    = (const float*)d_in[23];
    const float* ck0_w    = (const float*)d_in[24];
    const float* ck0_b    = (const float*)d_in[25];
    const float* tq0_w    = (const float*)d_in[26];
    const float* tq0_b    = (const float*)d_in[27];
    const float* tk0_w    = (const float*)d_in[28];
    const float* tk0_b    = (const float*)d_in[29];
    const float* tq1_w    = (const float*)d_in[30];
    const float* tq1_b    = (const float*)d_in[31];
    const float* tk1_w    = (const float*)d_in[32];
    const float* tk1_b    = (const float*)d_in[33];

    float* out = (float*)d_out;
    float* ws  = (float*)d_ws;

    const size_t NB  = (size_t)Bn * CFT;
    const size_t SNN = (size_t)Bn * Tn * Tn;          // 7,936,128 floats
    float* V       = ws;
    float* Q       = ws + NB;
    float* K       = ws + 2 * NB;
    float* Qp      = ws + 3 * NB;
    float* Kp      = ws + 4 * NB;
    float* S       = ws + 5 * NB;                     // SNN floats
    float* SPf     = S + 500000;                      // split-K / gram partials (3.45M)
    float* SaccF   = S + 4000000;                     // f P-sum (430,592)
    float* SaccC   = S + 4600000;                     // c P-sum (8,192)
    float* meanbuf = S + SNN;
    float* coef    = meanbuf + (size_t)Bn * RCn;
    float* SaccT   = coef + (size_t)4 * RCn * Bn;     // t P-sum (SNN), conditional
    bool fuseT = ws_size >= (5 * NB + 2 * SNN + 15360) * sizeof(float);

    {
        int total = Bn * FT;
        k_differ_qk<<<dim3((total + 255) / 256), dim3(256), 0, stream>>>(
            x, w_diff, b_diff, wq, bq, wk, bk, V, Q, K);
    }

    const float scF = 1.0f / sqrtf(1992.f);
    const float scC = 1.0f / sqrtf((float)FT);
    const float sc464 = 1.0f / sqrtf(464.f);
    const float sc232 = 1.0f / sqrtf(232.f);

    // ---- f branch: n=58, d=1992, sec=0. Two softmax rounds -> one apply.
    auto f_scores = [&](const float* Qv, const float* Kv, int first) {
        dim3 g1(1, 1, Bn * 8);
        k_scores_sk<<<g1, dim3(256), 0, stream>>>(Qv, Kv, SPf, Fn, 1992, 8, 256, CFT);
        k_scombine<<<dim3((Bn * Fn * Fn + 255) / 256), dim3(256), 0, stream>>>(SPf, S, Fn, 8);
        k_softmax<<<dim3(Bn), dim3(256), 0, stream>>>(S, SaccF, Fn, 1, scF, first);
    };
    f_scores(Q, K, 1);
    k_gemm<Fn, 12, 4><<<dim3(Bn * 10), dim3(256), 0, stream>>>(
        fq0_w, 0, fq0_b, Q, CFT, 1992, Qp, CFT, 0, 2, 5);
    k_gemm<Fn, 12, 4><<<dim3(Bn * 10), dim3(256), 0, stream>>>(
        fk0_w, 0, fk0_b, K, CFT, 1992, Kp, CFT, 0, 2, 5);
    f_scores(Qp, Kp, 0);
    k_gemm<Fn, 12, 4><<<dim3(Bn * 10), dim3(256), 0, stream>>>(
        SaccF, (long long)Fn * Fn, nullptr, V, CFT, 1992, out, OUTB, 0, 2, 5);

    // ---- c branch: n=8, d=FT, sec=1. Two softmax rounds -> one apply.
    auto c_scores = [&](const float* Qv, const float* Kv, int first) {
        k_gram8<<<dim3(Bn * C_LZ), dim3(256), 0, stream>>>(Qv, Kv, SPf);
        k_scombine<<<dim3((Bn * 64 + 255) / 256), dim3(256), 0, stream>>>(SPf, S, Cn, C_LZ);
        k_softmax<<<dim3(Bn), dim3(256), 0, stream>>>(S, SaccC, Cn, 1, scC, first);
    };
    c_scores(Q, K, 1);
    k_gemm<Cn, 8, 2><<<dim3(Bn * 29), dim3(256), 0, stream>>>(
        cq0_w, 0, cq0_b, Q, CFT, FT, Qp, CFT, 0, 29, 1);
    k_gemm<Cn, 8, 2><<<dim3(Bn * 29), dim3(256), 0, stream>>>(
        ck0_w, 0, ck0_b, K, CFT, FT, Kp, CFT, 0, 29, 1);
    c_scores(Qp, Kp, 0);
    k_gemm<Cn, 8, 2><<<dim3(Bn * 29), dim3(256), 0, stream>>>(
        SaccC, 64, nullptr, V, CFT, FT, out + CFT, OUTB, 0, 29, 1);

    // ---- t branch: n=249, dv=464, sec=2. Three rounds; fused into one apply
    // when the workspace has room for the 31.7 MB P-sum, else legacy 3-apply.
    float* tAcc = fuseT ? SaccT : nullptr;
    auto t_round = [&](const float* Qv, const float* Kv, int d, int sQ,
                       float sc, int round) {
        dim3 g1(2, 2, Bn);
        k_scores128<<<g1, dim3(256), 0, stream>>>(Qv, Kv, S, Tn, d, sQ);
        k_softmax<<<dim3(Bn * 4), dim3(256), 0, stream>>>(S, tAcc, Tn, 4, sc, round == 0);
        if (!fuseT) {
            k_gemm<Tn, 14, 4><<<dim3(Bn * 18), dim3(256), 0, stream>>>(
                S, (long long)Tn * Tn, nullptr, V, CFT, 464,
                out + 2 * CFT, OUTB, round > 0, 1, 18);
        }
    };
    t_round(Q, K, 464, CFT, sc464, 0);
    k_gemm<Tn, 14, 4><<<dim3(Bn * 18), dim3(256), 0, stream>>>(
        tq0_w, 0, tq0_b, Q, CFT, 464, Qp, CFT, 0, 1, 18);
    k_gemm<Tn, 14, 4><<<dim3(Bn * 18), dim3(256), 0, stream>>>(
        tk0_w, 0, tk0_b, K, CFT, 464, Kp, CFT, 0, 1, 18);
    t_round(Qp, Kp, 464, CFT, sc464, 1);
    k_gemm_s2<Tn, 8><<<dim3(Bn * 8), dim3(256), 0, stream>>>(
        tq1_w, tq1_b, Q, CFT, 464, 232, Qp, (long long)Tn * 232, 8);
    k_gemm_s2<Tn, 8><<<dim3(Bn * 8), dim3(256), 0, stream>>>(
        tk1_w, tk1_b, K, CFT, 464, 232, Kp, (long long)Tn * 232, 8);
    t_round(Qp, Kp, 232, Tn * 232, sc232, 2);
    if (fuseT) {
        k_gemm<Tn, 14, 4><<<dim3(Bn * 18), dim3(256), 0, stream>>>(
            SaccT, (long long)Tn * Tn, nullptr, V, CFT, 464,
            out + 2 * CFT, OUTB, 0, 1, 18);
    }

    // ---- xr residual path
    k_mean<<<dim3(Bn * RCn), dim3(256), 0, stream>>>(
        inp, w_res, b_res, bn_gamma, bn_beta, bn_mean, bn_var, meanbuf);
    k_coef<<<dim3(Bn), dim3(128), 0, stream>>>(meanbuf, dy_w1, dy_b1, dy_w2, dy_b2, coef);
    {
        int total = Bn * RCn * FT;
        k_xr_add<<<dim3((total + 255) / 256), dim3(256), 0, stream>>>(
            inp, w_res, b_res, bn_gamma, bn_beta, bn_mean, bn_var, coef, out);
    }
}

// Round 4
// 2622.932 us; speedup vs baseline: 1.8894x; 1.2708x over previous
//
#include <hip/hip_runtime.h>
#include <cmath>

#define Bn   128
#define Cn   8
#define Fn   58
#define Tn   249
#define RCn  24
#define FT   14442      // Fn*Tn
#define CFT  115536     // Cn*Fn*Tn
#define OUTB 346608     // 3*CFT per-batch output
#define IH   60
#define IW   251

// ---------------------------------------------------------------------------
// differ = concat([x[...,:1], W_diff@x + b_diff (shift) - x[...,:-1]], -1)
// Q = wq@differ + bq ; K = wk@differ + bk ; V = differ
// ---------------------------------------------------------------------------
__global__ void k_differ_qk(const float* __restrict__ x,
                            const float* __restrict__ w_diff, const float* __restrict__ b_diff,
                            const float* __restrict__ wq, const float* __restrict__ bq,
                            const float* __restrict__ wk, const float* __restrict__ bk,
                            float* __restrict__ V, float* __restrict__ Q, float* __restrict__ K) {
    int gid = blockIdx.x * blockDim.x + threadIdx.x;
    if (gid >= Bn * FT) return;
    int b  = gid / FT;
    int ft = gid % FT;
    int t  = ft % Tn;
    const float* xb = x + (size_t)b * CFT + ft;

    float xv[Cn], d[Cn];
    #pragma unroll
    for (int c = 0; c < Cn; c++) xv[c] = xb[c * FT];

    if (t == 0) {
        #pragma unroll
        for (int c = 0; c < Cn; c++) d[c] = xv[c];
    } else {
        #pragma unroll
        for (int o = 0; o < Cn; o++) {
            float s = b_diff[o];
            #pragma unroll
            for (int c = 0; c < Cn; c++) s += w_diff[o * Cn + c] * xv[c];
            d[o] = s - xb[o * FT - 1];
        }
    }

    float* Vb = V + (size_t)b * CFT + ft;
    float* Qb = Q + (size_t)b * CFT + ft;
    float* Kb = K + (size_t)b * CFT + ft;
    #pragma unroll
    for (int o = 0; o < Cn; o++) {
        Vb[o * FT] = d[o];
        float q = bq[o], k = bk[o];
        #pragma unroll
        for (int c = 0; c < Cn; c++) { q += wq[o * Cn + c] * d[c]; k += wk[o * Cn + c] * d[c]; }
        Qb[o * FT] = q;
        Kb[o * FT] = k;
    }
}

// ---------------------------------------------------------------------------
// Column-owner register GEMM v4 (R3 post-mortem: VGPR=56 left no room for
// load buffering -> one outstanding load/thread, full memory latency exposed
// per m-step -> 423us @ VALUBusy 16%).
//   - explicit 4-deep prefetch: four NAMED float4 regs rotated through the
//     m-loop (static indexing; compiler keeps vmcnt(3)-style waits).
//   - GW wave-aligned row-groups per block: lane util 45%->90% for dv=464,
//     and fewer X re-reads (t: 18x->8x, f: 5x->2x).
//   - LDS: group-aligned sub-rows (RGA mult of 4) -> b128 broadcast reads,
//     row width 34/10 words -> staging writes 4-way not 32-way conflicted.
// ---------------------------------------------------------------------------
template<int AN, int RG, int GW, int VL>
__global__ void __launch_bounds__(256, 4)
k_gemm(const float* __restrict__ A, long long aStride,   // 0 => batch-shared weights
       const float* __restrict__ bias,                   // nullptr => no bias
       const float* __restrict__ V, long long vStride, int dv,
       float* __restrict__ out, long long oStride, int add,
       int gx, int gy)
{
    constexpr int TPG = 256 / GW;
    constexpr int RGA = (RG + 3) & ~3;
    constexpr int RGP = GW * RGA + 2;
    __shared__ float As[64][RGP];

    int nblk = gridDim.x;
    int bid  = blockIdx.x;
    if ((nblk & 7) == 0) {               // bijective XCD swizzle
        int cpx = nblk >> 3;
        bid = (bid & 7) * cpx + (bid >> 3);
    }
    int gxy = gx * gy;
    int b   = bid / gxy;
    int rem = bid - b * gxy;
    int jb  = (rem / gx) * (GW * RG);
    int g   = threadIdx.x / TPG;         // wave-aligned group id
    int cl  = threadIdx.x % TPG;
    int j0  = jb + g * RG;
    int l   = (rem % gx) * (TPG * VL) + cl * VL;
    bool act = (l + VL <= dv);

    const float* Ab = A + (size_t)b * aStride;
    const float* Vb = V + (size_t)b * vStride + l;

    float acc[RG][VL];
    #pragma unroll
    for (int j = 0; j < RG; j++)
        #pragma unroll
        for (int e = 0; e < VL; e++) acc[j][e] = 0.f;

    for (int m0 = 0; m0 < AN; m0 += 64) {
        int mc = min(64, AN - m0);
        for (int idx = threadIdx.x; idx < GW * RG * 64; idx += 256) {
            int j = idx >> 6, mi = idx & 63;
            float w = 0.f;
            if (jb + j < AN && mi < mc) w = Ab[(size_t)(jb + j) * AN + m0 + mi];
            As[mi][(j / RG) * RGA + (j % RG)] = w;
        }
        __syncthreads();
        if (act) {
            const float* Vp = Vb + (size_t)m0 * dv;
            auto LD = [&](int i) -> float4 {
                const float* p = Vp + (size_t)min(i, mc - 1) * dv;
                if constexpr (VL == 4) {
                    return *(const float4*)p;
                } else {
                    float2 t = *(const float2*)p;
                    return make_float4(t.x, t.y, 0.f, 0.f);
                }
            };
            auto FMA = [&](int mm, float4 x) {
                const float* w = &As[mm][g * RGA];
                #pragma unroll
                for (int j = 0; j < RG; j++) {
                    float wv = w[j];
                    acc[j][0] += wv * x.x;
                    if constexpr (VL >= 2) acc[j][1] += wv * x.y;
                    if constexpr (VL >= 4) {
                        acc[j][2] += wv * x.z;
                        acc[j][3] += wv * x.w;
                    }
                }
            };
            float4 p0 = LD(0), p1 = LD(1), p2 = LD(2), p3 = LD(3);
            int mm = 0;
            for (; mm + 4 <= mc; mm += 4) {
                FMA(mm + 0, p0); p0 = LD(mm + 4);
                FMA(mm + 1, p1); p1 = LD(mm + 5);
                FMA(mm + 2, p2); p2 = LD(mm + 6);
                FMA(mm + 3, p3); p3 = LD(mm + 7);
            }
            if (mm     < mc) FMA(mm,     p0);
            if (mm + 1 < mc) FMA(mm + 1, p1);
            if (mm + 2 < mc) FMA(mm + 2, p2);
        }
        __syncthreads();
    }

    if (!act) return;
    float* ob = out + (size_t)b * oStride + l;
    #pragma unroll
    for (int j = 0; j < RG; j++) {
        if (j0 + j < AN) {
            float bv = bias ? bias[j0 + j] : 0.f;
            float* op = ob + (size_t)(j0 + j) * dv;
            if (add) {
                #pragma unroll
                for (int e = 0; e < VL; e++) op[e] += acc[j][e] + bv;
            } else {
                if constexpr (VL == 4) {
                    *(float4*)op = make_float4(acc[j][0] + bv, acc[j][1] + bv,
                                               acc[j][2] + bv, acc[j][3] + bv);
                } else {
                    *(float2*)op = make_float2(acc[j][0] + bv, acc[j][1] + bv);
                }
            }
        }
    }
}

// ---------------------------------------------------------------------------
// Stride-2 conv v4: wave-per-row-group layout (58/64 lanes active) + 2-mm
// explicit prefetch (4 float4 loads in flight).
// ---------------------------------------------------------------------------
template<int AN, int RGW>
__global__ void __launch_bounds__(256, 4)
k_gemm_s2(const float* __restrict__ W, const float* __restrict__ bias,
          const float* __restrict__ X, long long xStride, int d_in, int d_out,
          float* __restrict__ out, long long oStride, int gy)
{
    constexpr int BR = 4 * RGW;              // rows per block
    __shared__ float Ws[64][2 * BR + 2];

    int nblk = gridDim.x;
    int bid  = blockIdx.x;
    if ((nblk & 7) == 0) {
        int cpx = nblk >> 3;
        bid = (bid & 7) * cpx + (bid >> 3);
    }
    int b    = bid / gy;
    int jb   = (bid % gy) * BR;
    int w    = threadIdx.x >> 6;
    int lane = threadIdx.x & 63;
    int j0   = jb + w * RGW;
    int l4   = lane * 4;
    bool act = l4 < d_out;                   // d_out=232 -> lanes 0..57

    const float* Xb = X + (size_t)b * xStride + 2 * l4;

    float acc[RGW][4];
    #pragma unroll
    for (int j = 0; j < RGW; j++)
        #pragma unroll
        for (int e = 0; e < 4; e++) acc[j][e] = 0.f;

    for (int m0 = 0; m0 < AN; m0 += 64) {
        int mc = min(64, AN - m0);
        for (int idx = threadIdx.x; idx < 2 * BR * 64; idx += 256) {
            int mi = idx & 63, rest = idx >> 6;
            int rj = rest >> 1, tap = rest & 1;
            float wv = 0.f;
            if (jb + rj < AN && mi < mc)
                wv = W[((size_t)(jb + rj) * AN + m0 + mi) * 2 + tap];
            Ws[mi][2 * rj + tap] = wv;
        }
        __syncthreads();
        if (act) {
            const float* Xp = Xb + (size_t)m0 * d_in;
            auto FMAS = [&](int mm, float4 x0, float4 x1) {
                const float* wrow = &Ws[mm][2 * (w * RGW)];
                #pragma unroll
                for (int j = 0; j < RGW; j++) {
                    float w0 = wrow[2 * j], w1 = wrow[2 * j + 1];
                    acc[j][0] += w0 * x0.x + w1 * x0.y;
                    acc[j][1] += w0 * x0.z + w1 * x0.w;
                    acc[j][2] += w0 * x1.x + w1 * x1.y;
                    acc[j][3] += w0 * x1.z + w1 * x1.w;
                }
            };
            const float* q0 = Xp + (size_t)min(0, mc - 1) * d_in;
            const float* q1 = Xp + (size_t)min(1, mc - 1) * d_in;
            float4 a0 = *(const float4*)q0, b0 = *(const float4*)(q0 + 4);
            float4 a1 = *(const float4*)q1, b1 = *(const float4*)(q1 + 4);
            int mm = 0;
            for (; mm + 2 <= mc; mm += 2) {
                FMAS(mm, a0, b0);
                { const float* p = Xp + (size_t)min(mm + 2, mc - 1) * d_in;
                  a0 = *(const float4*)p; b0 = *(const float4*)(p + 4); }
                FMAS(mm + 1, a1, b1);
                { const float* p = Xp + (size_t)min(mm + 3, mc - 1) * d_in;
                  a1 = *(const float4*)p; b1 = *(const float4*)(p + 4); }
            }
            if (mm < mc) FMAS(mm, a0, b0);
        }
        __syncthreads();
    }

    if (!act) return;
    float* ob = out + (size_t)b * oStride + l4;
    #pragma unroll
    for (int j = 0; j < RGW; j++) {
        if (j0 + j < AN) {
            float bv = bias[j0 + j];
            *(float4*)(ob + (size_t)(j0 + j) * d_out) =
                make_float4(acc[j][0] + bv, acc[j][1] + bv,
                            acc[j][2] + bv, acc[j][3] + bv);
        }
    }
}

// ---------------------------------------------------------------------------
// t-branch scores: 128x128 tile, 8x8 per thread.
// ---------------------------------------------------------------------------
__global__ void __launch_bounds__(256, 4)
k_scores128(const float* __restrict__ Q, const float* __restrict__ K,
            float* __restrict__ S, int n, int d, int sQ) {
    __shared__ float Qs[16][132];
    __shared__ float Ks[16][132];
    int b  = blockIdx.z;
    int r0 = blockIdx.x * 128, c0 = blockIdx.y * 128;
    int tid = threadIdx.x;
    int tx = tid & 15, ty = tid >> 4;
    int lrow = tid >> 1;
    int lk   = (tid & 1) * 8;
    const float* Qr = Q + (size_t)b * sQ + (size_t)min(r0 + lrow, n - 1) * d;
    const float* Kr = K + (size_t)b * sQ + (size_t)min(c0 + lrow, n - 1) * d;

    float acc[8][8] = {};
    for (int kk = 0; kk < d; kk += 16) {
        #pragma unroll
        for (int h = 0; h < 2; h++) {
            int g = kk + lk + h * 4;
            float4 qv = make_float4(0.f, 0.f, 0.f, 0.f);
            float4 kv = make_float4(0.f, 0.f, 0.f, 0.f);
            if (g + 4 <= d) {                 // d % 4 == 0 for all uses
                qv = *(const float4*)(Qr + g);
                kv = *(const float4*)(Kr + g);
            }
            int kb = lk + h * 4;
            Qs[kb + 0][lrow] = qv.x; Qs[kb + 1][lrow] = qv.y;
            Qs[kb + 2][lrow] = qv.z; Qs[kb + 3][lrow] = qv.w;
            Ks[kb + 0][lrow] = kv.x; Ks[kb + 1][lrow] = kv.y;
            Ks[kb + 2][lrow] = kv.z; Ks[kb + 3][lrow] = kv.w;
        }
        __syncthreads();
        #pragma unroll
        for (int k = 0; k < 16; k++) {
            float4 qa = *(const float4*)&Qs[k][ty * 8];
            float4 qb = *(const float4*)&Qs[k][ty * 8 + 4];
            float4 ka = *(const float4*)&Ks[k][tx * 8];
            float4 kb4 = *(const float4*)&Ks[k][tx * 8 + 4];
            float aq[8] = {qa.x, qa.y, qa.z, qa.w, qb.x, qb.y, qb.z, qb.w};
            float ak[8] = {ka.x, ka.y, ka.z, ka.w, kb4.x, kb4.y, kb4.z, kb4.w};
            #pragma unroll
            for (int i = 0; i < 8; i++)
                #pragma unroll
                for (int j = 0; j < 8; j++) acc[i][j] += aq[i] * ak[j];
        }
        __syncthreads();
    }
    float* Sb = S + (size_t)b * n * n;
    #pragma unroll
    for (int i = 0; i < 8; i++) {
        int r = r0 + ty * 8 + i;
        if (r < n) {
            #pragma unroll
            for (int j = 0; j < 8; j++) {
                int c = c0 + tx * 8 + j;
                if (c < n) Sb[(size_t)r * n + c] = acc[i][j];
            }
        }
    }
}

// ---------------------------------------------------------------------------
// f-branch scores split-K (n=58 fits a 64-tile).
// ---------------------------------------------------------------------------
__global__ void __launch_bounds__(256)
k_scores_sk(const float* __restrict__ Q, const float* __restrict__ K,
            float* __restrict__ SP, int n, int d, int kz_n, int chunk, int sQ) {
    __shared__ float Qs[16][68];
    __shared__ float Ks[16][68];
    int bz = blockIdx.z;
    int b  = bz / kz_n, kz = bz % kz_n;
    int k0 = kz * chunk, k1 = min(d, k0 + chunk);
    int r0 = blockIdx.x * 64, c0 = blockIdx.y * 64;
    int tx = threadIdx.x & 15, ty = threadIdx.x >> 4;
    int lrow = threadIdx.x >> 2;
    int lk   = (threadIdx.x & 3) * 4;
    const float* Qr = Q + (size_t)b * sQ + (size_t)min(r0 + lrow, n - 1) * d;
    const float* Kr = K + (size_t)b * sQ + (size_t)min(c0 + lrow, n - 1) * d;
    bool qok = (r0 + lrow) < n;
    bool kok = (c0 + lrow) < n;
    float acc[4][4] = {};

    for (int kk = k0; kk < k1; kk += 16) {
        #pragma unroll
        for (int u = 0; u < 4; u++) {
            int gk = kk + lk + u;
            bool gv = gk < k1;
            Qs[lk + u][lrow] = (qok && gv) ? Qr[gk] : 0.f;
            Ks[lk + u][lrow] = (kok && gv) ? Kr[gk] : 0.f;
        }
        __syncthreads();
        #pragma unroll
        for (int k = 0; k < 16; k++) {
            float4 q4 = *(const float4*)&Qs[k][ty * 4];
            float4 k4 = *(const float4*)&Ks[k][tx * 4];
            float aq[4] = {q4.x, q4.y, q4.z, q4.w};
            float ak[4] = {k4.x, k4.y, k4.z, k4.w};
            #pragma unroll
            for (int i = 0; i < 4; i++)
                #pragma unroll
                for (int j = 0; j < 4; j++) acc[i][j] += aq[i] * ak[j];
        }
        __syncthreads();
    }
    float* Sb = SP + (size_t)bz * n * n;
    #pragma unroll
    for (int i = 0; i < 4; i++) {
        int r = r0 + ty * 4 + i;
        #pragma unroll
        for (int j = 0; j < 4; j++) {
            int c = c0 + tx * 4 + j;
            if (r < n && c < n) Sb[(size_t)r * n + c] = acc[i][j];
        }
    }
}

// ---------------------------------------------------------------------------
// Combine split-K partials (no scale — softmax folds 1/sqrt(d)).
// ---------------------------------------------------------------------------
__global__ void k_scombine(const float* __restrict__ SP, float* __restrict__ S,
                           int n, int kz_n) {
    int idx = blockIdx.x * 256 + threadIdx.x;
    int nn = n * n;
    if (idx >= Bn * nn) return;
    int b = idx / nn, rc = idx % nn;
    float s = 0.f;
    for (int kz = 0; kz < kz_n; kz++) s += SP[((size_t)b * kz_n + kz) * nn + rc];
    S[(size_t)b * nn + rc] = s;
}

// ---------------------------------------------------------------------------
// c-branch gram: 8x8 over d=FT, 8 l-chunks of partials.
// ---------------------------------------------------------------------------
#define C_LZ 8
__global__ void k_gram8(const float* __restrict__ Q, const float* __restrict__ K,
                        float* __restrict__ SP) {
    int b  = blockIdx.x / C_LZ;
    int lz = blockIdx.x % C_LZ;
    int g  = threadIdx.x >> 6;
    int p  = threadIdx.x & 63;
    int r  = p >> 3, c = p & 7;
    const float* Qb = Q + (size_t)b * CFT + (size_t)r * FT;
    const float* Kb = K + (size_t)b * CFT + (size_t)c * FT;
    int chunk = (FT + C_LZ - 1) / C_LZ;
    int l0 = lz * chunk, l1 = min(FT, l0 + chunk);
    float acc = 0.f;
    for (int l = l0 + g; l < l1; l += 4) acc += Qb[l] * Kb[l];
    __shared__ float red[256];
    red[threadIdx.x] = acc;
    __syncthreads();
    if (threadIdx.x < 64) {
        float s = red[p] + red[64 + p] + red[128 + p] + red[192 + p];
        SP[(size_t)blockIdx.x * 64 + p] = s;
    }
}

// ---------------------------------------------------------------------------
// column softmax (axis=1), folds 1/sqrt(d). Optional P-accumulation into
// Sacc so each branch needs ONE apply (distributivity).
// ---------------------------------------------------------------------------
__global__ void __launch_bounds__(256)
k_softmax(float* __restrict__ S, float* __restrict__ Sacc,
          int n, int cb, float scale, int first) {
    __shared__ float red[4][64];
    int b  = blockIdx.x / cb;
    int tc = threadIdx.x & 63;
    int g  = threadIdx.x >> 6;
    int c  = (blockIdx.x % cb) * 64 + tc;
    bool act = c < n;
    float* Sb = S + (size_t)b * n * n;

    float mx = -1e30f;
    if (act) for (int r = g; r < n; r += 4) mx = fmaxf(mx, Sb[(size_t)r * n + c]);
    red[g][tc] = mx;
    __syncthreads();
    mx = fmaxf(fmaxf(red[0][tc], red[1][tc]), fmaxf(red[2][tc], red[3][tc]));
    __syncthreads();

    float sum = 0.f;
    if (act) for (int r = g; r < n; r += 4) {
        float e = __expf((Sb[(size_t)r * n + c] - mx) * scale);
        Sb[(size_t)r * n + c] = e;
        sum += e;
    }
    red[g][tc] = sum;
    __syncthreads();
    float inv = 1.f / (red[0][tc] + red[1][tc] + red[2][tc] + red[3][tc]);
    if (act) {
        if (Sacc) {
            float* Ab = Sacc + (size_t)b * n * n;
            for (int r = g; r < n; r += 4) {
                float v = Sb[(size_t)r * n + c] * inv;
                size_t o = (size_t)r * n + c;
                Ab[o] = first ? v : (Ab[o] + v);
            }
        } else {
            for (int r = g; r < n; r += 4) Sb[(size_t)r * n + c] *= inv;
        }
    }
}

// ---------------------------------------------------------------------------
// xr spatial mean per (b, rc)
// ---------------------------------------------------------------------------
__global__ void k_mean(const float* __restrict__ inp, const float* __restrict__ w_res,
                       const float* __restrict__ b_res, const float* __restrict__ bn_gamma,
                       const float* __restrict__ bn_beta, const float* __restrict__ bn_mean,
                       const float* __restrict__ bn_var, float* __restrict__ meanbuf) {
    int b  = blockIdx.x / RCn;
    int rc = blockIdx.x % RCn;
    float w[9];
    #pragma unroll
    for (int i = 0; i < 9; i++) w[i] = w_res[rc * 9 + i];
    float g    = bn_gamma[rc] * rsqrtf(bn_var[rc] + 1e-5f);
    float bias = (b_res[rc] - bn_mean[rc]) * g + bn_beta[rc];
    const float* ib = inp + (size_t)b * IH * IW;

    float sum = 0.f;
    for (int idx = threadIdx.x; idx < FT; idx += 256) {
        int f = idx / Tn, t = idx % Tn;
        const float* p = ib + f * IW + t;
        float v = w[0]*p[0]     + w[1]*p[1]     + w[2]*p[2]
                + w[3]*p[IW]    + w[4]*p[IW+1]  + w[5]*p[IW+2]
                + w[6]*p[2*IW]  + w[7]*p[2*IW+1]+ w[8]*p[2*IW+2];
        sum += v * g + bias;
    }
    __shared__ float red[256];
    red[threadIdx.x] = sum;
    __syncthreads();
    for (int s = 128; s > 0; s >>= 1) {
        if (threadIdx.x < s) red[threadIdx.x] += red[threadIdx.x + s];
        __syncthreads();
    }
    if (threadIdx.x == 0) meanbuf[b * RCn + rc] = red[0] / (float)FT;
}

// ---------------------------------------------------------------------------
// dyReLU coefficient MLP
// ---------------------------------------------------------------------------
__global__ void k_coef(const float* __restrict__ meanbuf, const float* __restrict__ w1,
                       const float* __restrict__ b1, const float* __restrict__ w2,
                       const float* __restrict__ b2, float* __restrict__ coef) {
    int b = blockIdx.x;
    int k = threadIdx.x;
    if (k >= 4 * RCn) return;
    const float* th = meanbuf + b * RCn;
    float h[6];
    #pragma unroll
    for (int j = 0; j < 6; j++) {
        float s = b1[j];
        #pragma unroll
        for (int c = 0; c < RCn; c++) s += th[c] * w1[j * RCn + c];
        h[j] = fmaxf(s, 0.f);
    }
    float s = b2[k];
    #pragma unroll
    for (int j = 0; j < 6; j++) s += h[j] * w2[k * 6 + j];
    float g2 = 2.f / (1.f + __expf(-s)) - 1.f;
    const float lam[4] = {1.f, 1.f, 0.5f, 0.5f};
    const float ini[4] = {1.f, 0.f, 0.f, 0.f};
    coef[b * 96 + k] = g2 * lam[k & 3] + ini[k & 3];
}

// ---------------------------------------------------------------------------
// recompute conv+BN, apply dyReLU, out += xr
// ---------------------------------------------------------------------------
__global__ void k_xr_add(const float* __restrict__ inp, const float* __restrict__ w_res,
                         const float* __restrict__ b_res, const float* __restrict__ bn_gamma,
                         const float* __restrict__ bn_beta, const float* __restrict__ bn_mean,
                         const float* __restrict__ bn_var, const float* __restrict__ coef,
                         float* __restrict__ out) {
    int gid = blockIdx.x * blockDim.x + threadIdx.x;
    if (gid >= Bn * RCn * FT) return;
    int t   = gid % Tn;
    int tmp = gid / Tn;
    int f   = tmp % Fn;  tmp /= Fn;
    int rc  = tmp % RCn;
    int b   = tmp / RCn;

    const float* wp = w_res + rc * 9;
    float g    = bn_gamma[rc] * rsqrtf(bn_var[rc] + 1e-5f);
    float bias = (b_res[rc] - bn_mean[rc]) * g + bn_beta[rc];
    const float* p = inp + (size_t)b * IH * IW + f * IW + t;
    float v = wp[0]*p[0]    + wp[1]*p[1]      + wp[2]*p[2]
            + wp[3]*p[IW]   + wp[4]*p[IW+1]   + wp[5]*p[IW+2]
            + wp[6]*p[2*IW] + wp[7]*p[2*IW+1] + wp[8]*p[2*IW+2];
    float xv = v * g + bias;

    const float* cf = coef + ((size_t)b * RCn + rc) * 4;
    float r = fmaxf(xv * cf[0] + cf[2], xv * cf[1] + cf[3]);
    out[gid] += r;
}

// ---------------------------------------------------------------------------
extern "C" void kernel_launch(void* const* d_in, const int* in_sizes, int n_in,
                              void* d_out, int out_size, void* d_ws, size_t ws_size,
                              hipStream_t stream) {
    const float* x        = (const float*)d_in[0];
    const float* inp      = (const float*)d_in[1];
    const float* w_diff   = (const float*)d_in[2];
    const float* b_diff   = (const float*)d_in[3];
    const float* w_res    = (const float*)d_in[4];
    const float* b_res    = (const float*)d_in[5];
    const float* bn_gamma = (const float*)d_in[6];
    const float* bn_beta  = (const float*)d_in[7];
    const float* bn_mean  = (const float*)d_in[8];
    const float* bn_var   = (const float*)d_in[9];
    const float* dy_w1    = (const float*)d_in[10];
    const float* dy_b1    = (const float*)d_in[11];
    const float* dy_w2    = (const float*)d_in[12];
    const float* dy_b2    = (const float*)d_in[13];
    const float* wq       = (const float*)d_in[14];
    const float* bq       = (const float*)d_in[15];
    const float* wk       = (const float*)d_in[16];
    const float* bk       = (const float*)d_in[17];
    const float* fq0_w    = (const float*)d_in[18];
    const float* fq0_b    = (const float*)d_in[19];
    const float* fk0_w    = (const float*)d_in[20];
    const float* fk0_b    = (const float*)d_in[21];
    const float* cq0_w    = (const float*)d_in[22];
    const float* cq0_b    = (const float*)d_in[23];
    const float* ck0_w    = (const float*)d_in[24];
    const float* ck0_b    = (const float*)d_in[25];
    const float* tq0_w    = (const float*)d_in[26];
    const float* tq0_b    = (const float*)d_in[27];
    const float* tk0_w    = (const float*)d_in[28];
    const float* tk0_b    = (const float*)d_in[29];
    const float* tq1_w    = (const float*)d_in[30];
    const float* tq1_b    = (const float*)d_in[31];
    const float* tk1_w    = (const float*)d_in[32];
    const float* tk1_b    = (const float*)d_in[33];

    float* out = (float*)d_out;
    float* ws  = (float*)d_ws;

    const size_t NB  = (size_t)Bn * CFT;
    const size_t SNN = (size_t)Bn * Tn * Tn;          // 7,936,128 floats
    float* V       = ws;
    float* Q       = ws + NB;
    float* K       = ws + 2 * NB;
    float* Qp      = ws + 3 * NB;
    float* Kp      = ws + 4 * NB;
    float* S       = ws + 5 * NB;                     // SNN floats
    float* SPf     = S + 500000;                      // split-K / gram partials
    float* SaccF   = S + 4000000;                     // f P-sum (430,592)
    float* SaccC   = S + 4600000;                     // c P-sum (8,192)
    float* meanbuf = S + SNN;
    float* coef    = meanbuf + (size_t)Bn * RCn;
    float* SaccT   = coef + (size_t)4 * RCn * Bn;     // t P-sum (SNN), conditional
    bool fuseT = ws_size >= (5 * NB + 2 * SNN + 15360) * sizeof(float);

    {
        int total = Bn * FT;
        k_differ_qk<<<dim3((total + 255) / 256), dim3(256), 0, stream>>>(
            x, w_diff, b_diff, wq, bq, wk, bk, V, Q, K);
    }

    const float scF = 1.0f / sqrtf(1992.f);
    const float scC = 1.0f / sqrtf((float)FT);
    const float sc464 = 1.0f / sqrtf(464.f);
    const float sc232 = 1.0f / sqrtf(232.f);

    // ---- f branch: n=58, d=1992, sec=0. Two softmax rounds -> one apply.
    // config <58,15,2,4>: 30 rows/block, gx=4, gy=2 (X read 2x).
    auto f_scores = [&](const float* Qv, const float* Kv, int first) {
        dim3 g1(1, 1, Bn * 8);
        k_scores_sk<<<g1, dim3(256), 0, stream>>>(Qv, Kv, SPf, Fn, 1992, 8, 256, CFT);
        k_scombine<<<dim3((Bn * Fn * Fn + 255) / 256), dim3(256), 0, stream>>>(SPf, S, Fn, 8);
        k_softmax<<<dim3(Bn), dim3(256), 0, stream>>>(S, SaccF, Fn, 1, scF, first);
    };
    f_scores(Q, K, 1);
    k_gemm<Fn, 15, 2, 4><<<dim3(Bn * 8), dim3(256), 0, stream>>>(
        fq0_w, 0, fq0_b, Q, CFT, 1992, Qp, CFT, 0, 4, 2);
    k_gemm<Fn, 15, 2, 4><<<dim3(Bn * 8), dim3(256), 0, stream>>>(
        fk0_w, 0, fk0_b, K, CFT, 1992, Kp, CFT, 0, 4, 2);
    f_scores(Qp, Kp, 0);
    k_gemm<Fn, 15, 2, 4><<<dim3(Bn * 8), dim3(256), 0, stream>>>(
        SaccF, (long long)Fn * Fn, nullptr, V, CFT, 1992, out, OUTB, 0, 4, 2);

    // ---- c branch: n=8, d=FT, sec=1. Two softmax rounds -> one apply.
    auto c_scores = [&](const float* Qv, const float* Kv, int first) {
        k_gram8<<<dim3(Bn * C_LZ), dim3(256), 0, stream>>>(Qv, Kv, SPf);
        k_scombine<<<dim3((Bn * 64 + 255) / 256), dim3(256), 0, stream>>>(SPf, S, Cn, C_LZ);
        k_softmax<<<dim3(Bn), dim3(256), 0, stream>>>(S, SaccC, Cn, 1, scC, first);
    };
    c_scores(Q, K, 1);
    k_gemm<Cn, 8, 1, 2><<<dim3(Bn * 29), dim3(256), 0, stream>>>(
        cq0_w, 0, cq0_b, Q, CFT, FT, Qp, CFT, 0, 29, 1);
    k_gemm<Cn, 8, 1, 2><<<dim3(Bn * 29), dim3(256), 0, stream>>>(
        ck0_w, 0, ck0_b, K, CFT, FT, Kp, CFT, 0, 29, 1);
    c_scores(Qp, Kp, 0);
    k_gemm<Cn, 8, 1, 2><<<dim3(Bn * 29), dim3(256), 0, stream>>>(
        SaccC, 64, nullptr, V, CFT, FT, out + CFT, OUTB, 0, 29, 1);

    // ---- t branch: n=249, dv=464, sec=2. config <249,16,2,4>: 32 rows/block,
    // gx=1 (2x116 active threads), gy=8 (X read 8x).
    float* tAcc = fuseT ? SaccT : nullptr;
    auto t_round = [&](const float* Qv, const float* Kv, int d, int sQ,
                       float sc, int round) {
        dim3 g1(2, 2, Bn);
        k_scores128<<<g1, dim3(256), 0, stream>>>(Qv, Kv, S, Tn, d, sQ);
        k_softmax<<<dim3(Bn * 4), dim3(256), 0, stream>>>(S, tAcc, Tn, 4, sc, round == 0);
        if (!fuseT) {
            k_gemm<Tn, 16, 2, 4><<<dim3(Bn * 8), dim3(256), 0, stream>>>(
                S, (long long)Tn * Tn, nullptr, V, CFT, 464,
                out + 2 * CFT, OUTB, round > 0, 1, 8);
        }
    };
    t_round(Q, K, 464, CFT, sc464, 0);
    k_gemm<Tn, 16, 2, 4><<<dim3(Bn * 8), dim3(256), 0, stream>>>(
        tq0_w, 0, tq0_b, Q, CFT, 464, Qp, CFT, 0, 1, 8);
    k_gemm<Tn, 16, 2, 4><<<dim3(Bn * 8), dim3(256), 0, stream>>>(
        tk0_w, 0, tk0_b, K, CFT, 464, Kp, CFT, 0, 1, 8);
    t_round(Qp, Kp, 464, CFT, sc464, 1);
    k_gemm_s2<Tn, 8><<<dim3(Bn * 8), dim3(256), 0, stream>>>(
        tq1_w, tq1_b, Q, CFT, 464, 232, Qp, (long long)Tn * 232, 8);
    k_gemm_s2<Tn, 8><<<dim3(Bn * 8), dim3(256), 0, stream>>>(
        tk1_w, tk1_b, K, CFT, 464, 232, Kp, (long long)Tn * 232, 8);
    t_round(Qp, Kp, 232, Tn * 232, sc232, 2);
    if (fuseT) {
        k_gemm<Tn, 16, 2, 4><<<dim3(Bn * 8), dim3(256), 0, stream>>>(
            SaccT, (long long)Tn * Tn, nullptr, V, CFT, 464,
            out + 2 * CFT, OUTB, 0, 1, 8);
    }

    // ---- xr residual path
    k_mean<<<dim3(Bn * RCn), dim3(256), 0, stream>>>(
        inp, w_res, b_res, bn_gamma, bn_beta, bn_mean, bn_var, meanbuf);
    k_coef<<<dim3(Bn), dim3(128), 0, stream>>>(meanbuf, dy_w1, dy_b1, dy_w2, dy_b2, coef);
    {
        int total = Bn * RCn * FT;
        k_xr_add<<<dim3((total + 255) / 256), dim3(256), 0, stream>>>(
            inp, w_res, b_res, bn_gamma, bn_beta, bn_mean, bn_var, coef, out);
    }
}